// Round 20
// baseline (123.809 us; speedup 1.0000x reference)
//
#include <hip/hip_runtime.h>
#include <hip/hip_bf16.h>

// Problem constants (fixed shapes)
#define T_SEQ 1024
#define NBATCH 8
#define NHEAD 12
#define HD 64
#define CDIM 768
#define C3 2304

typedef __attribute__((ext_vector_type(8))) __bf16 bf16x8;
typedef __attribute__((ext_vector_type(4))) __bf16 bf16x4;
typedef __attribute__((ext_vector_type(2))) __bf16 bf16x2;
typedef __attribute__((ext_vector_type(4))) float  f32x4;
typedef __attribute__((ext_vector_type(16))) float f32x16;

__device__ __forceinline__ f32x4 mfma_bf16(bf16x8 a, bf16x8 b, f32x4 c) {
    return __builtin_amdgcn_mfma_f32_16x16x32_bf16(a, b, c, 0, 0, 0);
}
__device__ __forceinline__ f32x16 mfma32(bf16x8 a, bf16x8 b, f32x16 c) {
    return __builtin_amdgcn_mfma_f32_32x32x16_bf16(a, b, c, 0, 0, 0);
}

// async global->LDS, 16B per lane; LDS dest is wave-uniform base (+lane*16 implicit)
__device__ __forceinline__ void gload16(const void* g, void* l) {
    __builtin_amdgcn_global_load_lds(
        (const __attribute__((address_space(1))) unsigned int*)g,
        (__attribute__((address_space(3))) unsigned int*)l, 16, 0, 0);
}

// counted waitcnt — memory clobber orders memory ops; no sched_barrier (m141)
#define WAIT_VM(N)  asm volatile("s_waitcnt vmcnt(" #N ")" ::: "memory")
#define WAIT_LGKM0  asm volatile("s_waitcnt lgkmcnt(0)" ::: "memory")

// ---------------- fused preprocessing: x->bf16 AND both weight transposes ----------
__global__ __launch_bounds__(256) void prep(const float* __restrict__ x,
                                            __bf16* __restrict__ xb,
                                            const float* __restrict__ Wa,
                                            __bf16* __restrict__ Wat,
                                            const float* __restrict__ Wp,
                                            __bf16* __restrict__ Wpt) {
    __shared__ float tile[32][33];
    const int bx = blockIdx.x;
    if (bx < 6144) {
        int i = bx * 256 + threadIdx.x;          // covers 8192*768/4 exactly
        float4 v = ((const float4*)x)[i];
        bf16x4 o = { (__bf16)v.x, (__bf16)v.y, (__bf16)v.z, (__bf16)v.w };
        ((bf16x4*)xb)[i] = o;
        return;
    }
    const int b2 = bx - 6144;                    // 0..2303
    const int gx = b2 % 96, gy = b2 / 96;        // gx 0..95, gy 0..23
    const float* W;  __bf16* Wt;  int C, c0;
    if (gx < 72) { W = Wa; Wt = Wat; C = 2304; c0 = gx * 32; }
    else         { W = Wp; Wt = Wpt; C = 768;  c0 = (gx - 72) * 32; }
    const int r0 = gy * 32;
    const int tc = threadIdx.x & 31, tr = threadIdx.x >> 5;   // tr in 0..7
#pragma unroll
    for (int i = 0; i < 4; ++i)
        tile[tr + i * 8][tc] = W[(size_t)(r0 + tr + i * 8) * C + c0 + tc];
    __syncthreads();
#pragma unroll
    for (int i = 0; i < 4; ++i)
        Wt[(size_t)(c0 + tr + i * 8) * 768 + r0 + tc] = (__bf16)tile[tc][tr + i * 8];
}

// ---------------- QKV GEMM: 256x256 tile, 1024 thr (16 waves, 4x4) -----------------
// Halved staged-bytes-per-FLOP vs 128^2 (guide regime: 256^2+2ph = 682 TF vs ~612).
// Wave-tile 64x64 = 2x2 frags of 32x32 (R8-proven per-wave code, ~84 VGPR -> fits
// 4 waves/SIMD). 3-slot LDS = 96KB -> 1 block/CU, 16 waves fill the CU. Staging is
// uniform: 1 A-chunk + 1 B-chunk per thread per tile -> counted vmcnt 4/2/0
// (prologue 6 outstanding; WAIT_VM(4) at top drains tile t, leaves t+1,t+2).
// Grid 288 = 8 XCDs x 36; xcd owns 4 m-panels (1.5MB A slice, L2-resident).
__global__ __launch_bounds__(1024) void gemm_qkv(const __bf16* __restrict__ A,
                                                 const __bf16* __restrict__ Bt,
                                                 const float* __restrict__ bias,
                                                 __bf16* __restrict__ Cout,
                                                 int M, int N, int K) {
    __shared__ __align__(16) __bf16 sA[3][256 * 32];
    __shared__ __align__(16) __bf16 sB[3][256 * 32];
    const int t = threadIdx.x, l = t & 63, w = t >> 6;     // w in 0..15
    const int l31 = l & 31, lh = l >> 5;
    const int wr = w >> 2, wc = w & 3;                     // 4x4 wave grid, 64x64 each
    const int xcd = blockIdx.x & 7;
    const int local = blockIdx.x >> 3;                     // 0..35
    const int m0 = (xcd * 4 + (local & 3)) * 256;          // 32 m-panels, 4 per XCD
    const int n0 = (local >> 2) * 256;                     // 9 n-panels

    // staging: chunk idx = t (0..1023) -> row r = t>>2 (0..255), chunk c = t&3;
    // fetch global chunk c ^ s(r), s(r) = (r&3)^((r>>2)&3); reads apply same XOR.
    const int r_st = t >> 2;
    const int sw_st = (r_st & 3) ^ ((r_st >> 2) & 3);
    const int g_off = ((t & 3) ^ sw_st) << 3;
    const int sw_rd = (l31 & 3) ^ ((l31 >> 2) & 3);        // frag row = base + l31, base%32==0

    f32x16 acc[2][2];
#pragma unroll
    for (int m = 0; m < 2; ++m)
#pragma unroll
        for (int n = 0; n < 2; ++n)
#pragma unroll
            for (int r = 0; r < 16; ++r) acc[m][n][r] = 0.f;

    const int nk = K >> 5;   // 24

    // prologue: stage tiles 0,1,2 (1 A-chunk + 1 B-chunk per thread each)
#pragma unroll
    for (int s = 0; s < 3; ++s) {
        const int k0 = s << 5;
        gload16(A + (size_t)(m0 + r_st) * K + k0 + g_off,
                (char*)&sA[s][0] + (w * 64) * 16);
        gload16(Bt + (size_t)(n0 + r_st) * K + k0 + g_off,
                (char*)&sB[s][0] + (w * 64) * 16);
    }

    int cur = 0;
    for (int kt = 0; kt < nk; ++kt) {
        if (kt + 2 < nk)      WAIT_VM(4);      // tile kt landed; kt+1, kt+2 in flight
        else if (kt + 1 < nk) WAIT_VM(2);
        else                  WAIT_VM(0);
        __builtin_amdgcn_s_barrier();

        bf16x8 af[2][2], bg[2][2];
#pragma unroll
        for (int m = 0; m < 2; ++m)
#pragma unroll
            for (int ks = 0; ks < 2; ++ks)
                af[m][ks] = *(const bf16x8*)(&sA[cur][(wr * 64 + m * 32 + l31) * 32
                                                      + ((((ks << 1) | lh) ^ sw_rd) << 3)]);
#pragma unroll
        for (int n = 0; n < 2; ++n)
#pragma unroll
            for (int ks = 0; ks < 2; ++ks)
                bg[n][ks] = *(const bf16x8*)(&sB[cur][(wc * 64 + n * 32 + l31) * 32
                                                      + ((((ks << 1) | lh) ^ sw_rd) << 3)]);

#pragma unroll
        for (int ks = 0; ks < 2; ++ks)
#pragma unroll
            for (int m = 0; m < 2; ++m)
#pragma unroll
                for (int n = 0; n < 2; ++n)
                    acc[m][n] = mfma32(af[m][ks], bg[n][ks], acc[m][n]);

        WAIT_LGKM0;
        __builtin_amdgcn_s_barrier();

        if (kt + 3 < nk) {                     // refill buf[cur] with tile kt+3
            const int k0 = (kt + 3) << 5;
            gload16(A + (size_t)(m0 + r_st) * K + k0 + g_off,
                    (char*)&sA[cur][0] + (w * 64) * 16);
            gload16(Bt + (size_t)(n0 + r_st) * K + k0 + g_off,
                    (char*)&sB[cur][0] + (w * 64) * 16);
        }
        cur = (cur == 2) ? 0 : cur + 1;
    }

    // epilogue: 32x32 C layout (m74/m101): col = l31, row = (r&3)+8*(r>>2)+4*lh
#pragma unroll
    for (int n = 0; n < 2; ++n) {
        int col = n0 + wc * 64 + n * 32 + l31;
        float bv = bias[col];
#pragma unroll
        for (int m = 0; m < 2; ++m) {
            int rbase = m0 + wr * 64 + m * 32 + 4 * lh;
#pragma unroll
            for (int r = 0; r < 16; ++r) {
                int row = rbase + (r & 3) + 8 * (r >> 2);
                Cout[(size_t)row * N + col] = (__bf16)(acc[m][n][r] + bv);
            }
        }
    }
}

// ---------------- proj GEMM: 64x128 tile -> 768 blocks = exactly 3/CU (R17) -------
__global__ __launch_bounds__(256) void gemm_proj(const __bf16* __restrict__ A,
                                                 const __bf16* __restrict__ Bt,
                                                 const float* __restrict__ bias,
                                                 float* __restrict__ Cout,
                                                 int M, int N, int K) {
    __shared__ __align__(16) __bf16 sA[3][64 * 32];
    __shared__ __align__(16) __bf16 sB[3][128 * 32];
    const int t = threadIdx.x, l = t & 63, w = t >> 6;
    const int l31 = l & 31, lh = l >> 5;
    const int wr = w >> 1, wc = w & 1;
    const int xcd = blockIdx.x & 7;
    const int local = blockIdx.x >> 3;                 // 0..95
    const int m0 = (xcd * 16 + (local & 15)) * 64;     // 128 m-panels
    const int n0 = (local >> 4) * 128;                 // 6 n-panels

    const int r_st = t >> 2;
    const int sw_st = (r_st & 3) ^ ((r_st >> 2) & 3);
    const int g_off = ((t & 3) ^ sw_st) << 3;
    const int sw_rd = (l31 & 3) ^ ((l31 >> 2) & 3);

    f32x16 acc[2];
#pragma unroll
    for (int n = 0; n < 2; ++n)
#pragma unroll
        for (int r = 0; r < 16; ++r) acc[n][r] = 0.f;

    const int nk = K >> 5;   // 24

#pragma unroll
    for (int s = 0; s < 3; ++s) {
        const int k0 = s << 5;
        gload16(A + (size_t)(m0 + r_st) * K + k0 + g_off,
                (char*)&sA[s][0] + (w * 64) * 16);
#pragma unroll
        for (int i = 0; i < 2; ++i)
            gload16(Bt + (size_t)(n0 + i * 64 + r_st) * K + k0 + g_off,
                    (char*)&sB[s][0] + (i * 256 + w * 64) * 16);
    }

    int cur = 0;
    for (int kt = 0; kt < nk; ++kt) {
        if (kt + 2 < nk)      WAIT_VM(6);
        else if (kt + 1 < nk) WAIT_VM(3);
        else                  WAIT_VM(0);
        __builtin_amdgcn_s_barrier();

        bf16x8 af[2], bg[2][2];
#pragma unroll
        for (int ks = 0; ks < 2; ++ks)
            af[ks] = *(const bf16x8*)(&sA[cur][(wr * 32 + l31) * 32
                                              + ((((ks << 1) | lh) ^ sw_rd) << 3)]);
#pragma unroll
        for (int n = 0; n < 2; ++n)
#pragma unroll
            for (int ks = 0; ks < 2; ++ks)
                bg[n][ks] = *(const bf16x8*)(&sB[cur][(wc * 64 + n * 32 + l31) * 32
                                                      + ((((ks << 1) | lh) ^ sw_rd) << 3)]);

#pragma unroll
        for (int ks = 0; ks < 2; ++ks)
#pragma unroll
            for (int n = 0; n < 2; ++n)
                acc[n] = mfma32(af[ks], bg[n][ks], acc[n]);

        WAIT_LGKM0;
        __builtin_amdgcn_s_barrier();

        if (kt + 3 < nk) {
            const int k0 = (kt + 3) << 5;
            gload16(A + (size_t)(m0 + r_st) * K + k0 + g_off,
                    (char*)&sA[cur][0] + (w * 64) * 16);
#pragma unroll
            for (int i = 0; i < 2; ++i)
                gload16(Bt + (size_t)(n0 + i * 64 + r_st) * K + k0 + g_off,
                        (char*)&sB[cur][0] + (i * 256 + w * 64) * 16);
        }
        cur = (cur == 2) ? 0 : cur + 1;
    }

#pragma unroll
    for (int n = 0; n < 2; ++n) {
        int col = n0 + wc * 64 + n * 32 + l31;
        float bv = bias[col];
        int rbase = m0 + wr * 32 + 4 * lh;
#pragma unroll
        for (int r = 0; r < 16; ++r) {
            int row = rbase + (r & 3) + 8 * (r >> 2);
            Cout[(size_t)row * N + col] = acc[n][r] + bv;
        }
    }
}

// ---------------- causal flash attention — FUSED job pair (R19-proven) -------------
__global__ __launch_bounds__(256, 2) void attn_fwd(const __bf16* __restrict__ qkv,
                                                   __bf16* __restrict__ y) {
    const int tid = threadIdx.x, l = tid & 63, w = tid >> 6;
    const int lr = l & 15, lk = l >> 4;
    const int r7 = lr & 7;
    const int bid = blockIdx.x;
    const int pr = bid / 96;                 // 0..7
    const int hb = bid % 96;
    const int h = hb % NHEAD;
    const int b = hb / NHEAD;

    __shared__ __align__(16) __bf16 sK[2][64][64];   // chunk-swizzled: phys c = log c ^ (row&7)
    __shared__ __align__(16) __bf16 sV[2][64][64];   // [d][key], XOR-swizzled columns
    __shared__ __align__(16) __bf16 sP[4][16][72];   // per-wave P tile [q][key]

    const size_t baseQ = (size_t)b * T_SEQ * C3 + h * HD;
    const __bf16* Kp = qkv + baseQ + CDIM;
    const __bf16* Vp = qkv + baseQ + 2 * CDIM;

    const int vk0 = tid >> 3;
    const int vc = (tid & 7) << 3;
    const int vg = tid & 7;
    const int krow = tid >> 3;
    const int kchunk = (tid & 7) ^ ((tid >> 3) & 7);

    const int q0A = pr * 64, q0B = (15 - pr) * 64;
    const int ntB = 16 - pr;                 // KV tiles 0..15-pr
    const int qA = q0A + w * 16 + lr;
    const int qB = q0B + w * 16 + lr;

    const size_t rowQA = baseQ + (size_t)(q0A + w * 16 + lr) * C3;
    const size_t rowQB = baseQ + (size_t)(q0B + w * 16 + lr) * C3;
    bf16x8 qaA0 = *(const bf16x8*)(qkv + rowQA + lk * 8);
    bf16x8 qaA1 = *(const bf16x8*)(qkv + rowQA + 32 + lk * 8);
    bf16x8 qaB0 = *(const bf16x8*)(qkv + rowQB + lk * 8);
    bf16x8 qaB1 = *(const bf16x8*)(qkv + rowQB + 32 + lk * 8);
#pragma unroll
    for (int e = 0; e < 8; ++e) {
        qaA0[e] = (__bf16)((float)qaA0[e] * 0.125f);
        qaA1[e] = (__bf16)((float)qaA1[e] * 0.125f);
        qaB0[e] = (__bf16)((float)qaB0[e] * 0.125f);
        qaB1[e] = (__bf16)((float)qaB1[e] * 0.125f);
    }

    f32x4 accA[4], accB[4];
#pragma unroll
    for (int fd = 0; fd < 4; ++fd) {
        accA[fd] = f32x4{0.f, 0.f, 0.f, 0.f};
        accB[fd] = f32x4{0.f, 0.f, 0.f, 0.f};
    }
    float mA = -1e30f, lA = 0.f, mB = -1e30f, lB = 0.f;

    bf16x8 vreg[2];
#pragma unroll
    for (int i = 0; i < 2; ++i)
        vreg[i] = *(const bf16x8*)(Vp + (size_t)(i * 32 + vk0) * C3 + vc);
#pragma unroll
    for (int i = 0; i < 2; ++i)
        gload16(Kp + (size_t)(i * 32 + krow) * C3 + kchunk * 8,
                (char*)&sK[0][0][0] + (i * 256 + w * 64) * 16);
#pragma unroll
    for (int i = 0; i < 2; ++i) {
        int key = i * 32 + vk0;
#pragma unroll
        for (int e = 0; e < 8; ++e)
            sV[0][vc + e][key ^ ((e ^ vg) << 3)] = vreg[i][e];
    }
    __syncthreads();

#pragma unroll 1
    for (int t = 0; t < ntB; ++t) {
        const int kv0 = t * 64;
        const int cur = t & 1, nxt = cur ^ 1;
        const bool pre = (t + 1 < ntB);
        if (pre) {
            const int kvp = kv0 + 64;
#pragma unroll
            for (int i = 0; i < 2; ++i)
                vreg[i] = *(const bf16x8*)(Vp + (size_t)(kvp + i * 32 + vk0) * C3 + vc);
#pragma unroll
            for (int i = 0; i < 2; ++i)
                gload16(Kp + (size_t)(kvp + i * 32 + krow) * C3 + kchunk * 8,
                        (char*)&sK[nxt][0][0] + (i * 256 + w * 64) * 16);
        }

        // ================= Q-tile B (always active) =================
        {
            f32x4 s[4];
            __builtin_amdgcn_s_setprio(1);
#pragma unroll
            for (int fc = 0; fc < 4; ++fc) {
                const __bf16* kr = &sK[cur][fc * 16 + lr][0];
                bf16x8 k0 = *(const bf16x8*)(kr + ((lk ^ r7) << 3));
                bf16x8 k1 = *(const bf16x8*)(kr + (((4 + lk) ^ r7) << 3));
                f32x4 z = f32x4{0.f, 0.f, 0.f, 0.f};
                z = mfma_bf16(k0, qaB0, z);
                z = mfma_bf16(k1, qaB1, z);
                s[fc] = z;
            }
            __builtin_amdgcn_s_setprio(0);
            float ps[4][4];
#pragma unroll
            for (int fc = 0; fc < 4; ++fc)
#pragma unroll
                for (int j = 0; j < 4; ++j) ps[fc][j] = s[fc][j];
            if (t == ntB - 1) {
#pragma unroll
                for (int fc = 0; fc < 4; ++fc)
#pragma unroll
                    for (int j = 0; j < 4; ++j) {
                        int key = kv0 + fc * 16 + lk * 4 + j;
                        if (key > qB) ps[fc][j] = -1e30f;
                    }
            }
            float mfc[4];
#pragma unroll
            for (int fc = 0; fc < 4; ++fc)
                mfc[fc] = fmaxf(fmaxf(ps[fc][0], ps[fc][1]), fmaxf(ps[fc][2], ps[fc][3]));
            float mt = fmaxf(fmaxf(mfc[0], mfc[1]), fmaxf(mfc[2], mfc[3]));
            mt = fmaxf(mt, __shfl_xor(mt, 16, 64));
            mt = fmaxf(mt, __shfl_xor(mt, 32, 64));
            if (!__all(mt - mB <= 8.f)) {
                const float mn = fmaxf(mB, mt);
                const float corr = __expf(mB - mn);
                mB = mn;
                lB *= corr;
                float cj[4];
#pragma unroll
                for (int j = 0; j < 4; ++j) cj[j] = __shfl(corr, lk * 4 + j, 64);
#pragma unroll
                for (int fd = 0; fd < 4; ++fd)
#pragma unroll
                    for (int j = 0; j < 4; ++j) accB[fd][j] *= cj[j];
            }
            float rs = 0.f;
#pragma unroll
            for (int fc = 0; fc < 4; ++fc)
#pragma unroll
                for (int j = 0; j < 4; ++j) {
                    float p = __expf(ps[fc][j] - mB);
                    ps[fc][j] = p;
                    rs += p;
                }
            rs += __shfl_xor(rs, 16, 64);
            rs += __shfl_xor(rs, 32, 64);
            lB += rs;
#pragma unroll
            for (int fc = 0; fc < 4; ++fc)
#pragma unroll
                for (int jp = 0; jp < 2; ++jp) {
                    bf16x2 pk = { (__bf16)ps[fc][jp * 2], (__bf16)ps[fc][jp * 2 + 1] };
                    *(bf16x2*)&sP[w][lr][fc * 16 + lk * 4 + jp * 2] = pk;
                }
            __builtin_amdgcn_s_setprio(1);
#pragma unroll
            for (int ks = 0; ks < 2; ++ks) {
                bf16x8 pa = *(const bf16x8*)&sP[w][lr][ks * 32 + lk * 8];
#pragma unroll
                for (int fd = 0; fd < 4; ++fd) {
                    int d = fd * 16 + lr;
                    int sw = ((d & 7) ^ ((d >> 3) & 7)) << 3;
                    bf16x8 vb = *(const bf16x8*)&sV[cur][d][(ks * 32 + lk * 8) ^ sw];
                    accB[fd] = mfma_bf16(pa, vb, accB[fd]);
                }
            }
            __builtin_amdgcn_s_setprio(0);
        }

        // ================= Q-tile A (shared prefix t <= pr) =================
        if (t <= pr) {
            f32x4 s[4];
            __builtin_amdgcn_s_setprio(1);
#pragma unroll
            for (int fc = 0; fc < 4; ++fc) {
                const __bf16* kr = &sK[cur][fc * 16 + lr][0];
                bf16x8 k0 = *(const bf16x8*)(kr + ((lk ^ r7) << 3));
                bf16x8 k1 = *(const bf16x8*)(kr + (((4 + lk) ^ r7) << 3));
                f32x4 z = f32x4{0.f, 0.f, 0.f, 0.f};
                z = mfma_bf16(k0, qaA0, z);
                z = mfma_bf16(k1, qaA1, z);
                s[fc] = z;
            }
            __builtin_amdgcn_s_setprio(0);
            float ps[4][4];
#pragma unroll
            for (int fc = 0; fc < 4; ++fc)
#pragma unroll
                for (int j = 0; j < 4; ++j) ps[fc][j] = s[fc][j];
            if (t == pr) {
#pragma unroll
                for (int fc = 0; fc < 4; ++fc)
#pragma unroll
                    for (int j = 0; j < 4; ++j) {
                        int key = kv0 + fc * 16 + lk * 4 + j;
                        if (key > qA) ps[fc][j] = -1e30f;
                    }
            }
            float mfc[4];
#pragma unroll
            for (int fc = 0; fc < 4; ++fc)
                mfc[fc] = fmaxf(fmaxf(ps[fc][0], ps[fc][1]), fmaxf(ps[fc][2], ps[fc][3]));
            float mt = fmaxf(fmaxf(mfc[0], mfc[1]), fmaxf(mfc[2], mfc[3]));
            mt = fmaxf(mt, __shfl_xor(mt, 16, 64));
            mt = fmaxf(mt, __shfl_xor(mt, 32, 64));
            if (!__all(mt - mA <= 8.f)) {
                const float mn = fmaxf(mA, mt);
                const float corr = __expf(mA - mn);
                mA = mn;
                lA *= corr;
                float cj[4];
#pragma unroll
                for (int j = 0; j < 4; ++j) cj[j] = __shfl(corr, lk * 4 + j, 64);
#pragma unroll
                for (int fd = 0; fd < 4; ++fd)
#pragma unroll
                    for (int j = 0; j < 4; ++j) accA[fd][j] *= cj[j];
            }
            float rs = 0.f;
#pragma unroll
            for (int fc = 0; fc < 4; ++fc)
#pragma unroll
                for (int j = 0; j < 4; ++j) {
                    float p = __expf(ps[fc][j] - mA);
                    ps[fc][j] = p;
                    rs += p;
                }
            rs += __shfl_xor(rs, 16, 64);
            rs += __shfl_xor(rs, 32, 64);
            lA += rs;
#pragma unroll
            for (int fc = 0; fc < 4; ++fc)
#pragma unroll
                for (int jp = 0; jp < 2; ++jp) {
                    bf16x2 pk = { (__bf16)ps[fc][jp * 2], (__bf16)ps[fc][jp * 2 + 1] };
                    *(bf16x2*)&sP[w][lr][fc * 16 + lk * 4 + jp * 2] = pk;
                }
            __builtin_amdgcn_s_setprio(1);
#pragma unroll
            for (int ks = 0; ks < 2; ++ks) {
                bf16x8 pa = *(const bf16x8*)&sP[w][lr][ks * 32 + lk * 8];
#pragma unroll
                for (int fd = 0; fd < 4; ++fd) {
                    int d = fd * 16 + lr;
                    int sw = ((d & 7) ^ ((d >> 3) & 7)) << 3;
                    bf16x8 vb = *(const bf16x8*)&sV[cur][d][(ks * 32 + lk * 8) ^ sw];
                    accA[fd] = mfma_bf16(pa, vb, accA[fd]);
                }
            }
            __builtin_amdgcn_s_setprio(0);
        }

        if (pre) {
#pragma unroll
            for (int i = 0; i < 2; ++i) {
                int key = i * 32 + vk0;
#pragma unroll
                for (int e = 0; e < 8; ++e)
                    sV[nxt][vc + e][key ^ ((e ^ vg) << 3)] = vreg[i][e];
            }
        }
        __syncthreads();
    }

    {
        float linv[4];
#pragma unroll
        for (int j = 0; j < 4; ++j) linv[j] = 1.f / __shfl(lA, lk * 4 + j, 64);
        const size_t yrow0 = (size_t)(b * T_SEQ + q0A + w * 16 + lk * 4);
#pragma unroll
        for (int fd = 0; fd < 4; ++fd) {
            int col = h * HD + fd * 16 + lr;
#pragma unroll
            for (int j = 0; j < 4; ++j)
                y[(yrow0 + j) * CDIM + col] = (__bf16)(accA[fd][j] * linv[j]);
        }
    }
    {
        float linv[4];
#pragma unroll
        for (int j = 0; j < 4; ++j) linv[j] = 1.f / __shfl(lB, lk * 4 + j, 64);
        const size_t yrow0 = (size_t)(b * T_SEQ + q0B + w * 16 + lk * 4);
#pragma unroll
        for (int fd = 0; fd < 4; ++fd) {
            int col = h * HD + fd * 16 + lr;
#pragma unroll
            for (int j = 0; j < 4; ++j)
                y[(yrow0 + j) * CDIM + col] = (__bf16)(accB[fd][j] * linv[j]);
        }
    }
}

// ---------------- launch ----------------
extern "C" void kernel_launch(void* const* d_in, const int* in_sizes, int n_in,
                              void* d_out, int out_size, void* d_ws, size_t ws_size,
                              hipStream_t stream) {
    const float* x      = (const float*)d_in[0];
    const float* W_attn = (const float*)d_in[1];
    const float* b_attn = (const float*)d_in[2];
    const float* W_proj = (const float*)d_in[3];
    const float* b_proj = (const float*)d_in[4];

    __bf16* xb  = (__bf16*)d_ws;                       // [8192][768]
    __bf16* Wat = xb  + (size_t)8192 * 768;            // [2304][768]  (W_attn^T)
    __bf16* Wpt = Wat + (size_t)2304 * 768;            // [768][768]   (W_proj^T)
    __bf16* qkv = Wpt + (size_t)768 * 768;             // [8192][2304]
    __bf16* yb  = qkv + (size_t)8192 * 2304;           // [8192][768]

    prep<<<6144 + 2304, 256, 0, stream>>>(x, xb, W_attn, Wat, W_proj, Wpt);
    // QKV: 32 m-panels x 9 n-panels = 288 blocks (1/CU, 16 waves fill the CU)
    gemm_qkv<<<288, 1024, 0, stream>>>(xb, Wat, b_attn, qkv, 8192, 2304, 768);
    attn_fwd<<<NBATCH * NHEAD * 8, 256, 0, stream>>>(qkv, yb);
    gemm_proj<<<768, 256, 0, stream>>>(yb, Wpt, b_proj, (float*)d_out, 8192, 768, 768);
}

// Round 21
// 108.290 us; speedup vs baseline: 1.1433x; 1.1433x over previous
//
#include <hip/hip_runtime.h>
#include <hip/hip_bf16.h>

// Problem constants (fixed shapes)
#define T_SEQ 1024
#define NBATCH 8
#define NHEAD 12
#define HD 64
#define CDIM 768
#define C3 2304

typedef __attribute__((ext_vector_type(8))) __bf16 bf16x8;
typedef __attribute__((ext_vector_type(4))) __bf16 bf16x4;
typedef __attribute__((ext_vector_type(2))) __bf16 bf16x2;
typedef __attribute__((ext_vector_type(4))) float  f32x4;
typedef __attribute__((ext_vector_type(16))) float f32x16;

__device__ __forceinline__ f32x4 mfma_bf16(bf16x8 a, bf16x8 b, f32x4 c) {
    return __builtin_amdgcn_mfma_f32_16x16x32_bf16(a, b, c, 0, 0, 0);
}
__device__ __forceinline__ f32x16 mfma32(bf16x8 a, bf16x8 b, f32x16 c) {
    return __builtin_amdgcn_mfma_f32_32x32x16_bf16(a, b, c, 0, 0, 0);
}

// async global->LDS, 16B per lane; LDS dest is wave-uniform base (+lane*16 implicit)
__device__ __forceinline__ void gload16(const void* g, void* l) {
    __builtin_amdgcn_global_load_lds(
        (const __attribute__((address_space(1))) unsigned int*)g,
        (__attribute__((address_space(3))) unsigned int*)l, 16, 0, 0);
}

// counted waitcnt — memory clobber orders memory ops; no sched_barrier (m141)
#define WAIT_VM(N)  asm volatile("s_waitcnt vmcnt(" #N ")" ::: "memory")
#define WAIT_LGKM0  asm volatile("s_waitcnt lgkmcnt(0)" ::: "memory")

// ---------------- fused preprocessing: x->bf16 AND both weight transposes ----------
__global__ __launch_bounds__(256) void prep(const float* __restrict__ x,
                                            __bf16* __restrict__ xb,
                                            const float* __restrict__ Wa,
                                            __bf16* __restrict__ Wat,
                                            const float* __restrict__ Wp,
                                            __bf16* __restrict__ Wpt) {
    __shared__ float tile[32][33];
    const int bx = blockIdx.x;
    if (bx < 6144) {
        int i = bx * 256 + threadIdx.x;          // covers 8192*768/4 exactly
        float4 v = ((const float4*)x)[i];
        bf16x4 o = { (__bf16)v.x, (__bf16)v.y, (__bf16)v.z, (__bf16)v.w };
        ((bf16x4*)xb)[i] = o;
        return;
    }
    const int b2 = bx - 6144;                    // 0..2303
    const int gx = b2 % 96, gy = b2 / 96;        // gx 0..95, gy 0..23
    const float* W;  __bf16* Wt;  int C, c0;
    if (gx < 72) { W = Wa; Wt = Wat; C = 2304; c0 = gx * 32; }
    else         { W = Wp; Wt = Wpt; C = 768;  c0 = (gx - 72) * 32; }
    const int r0 = gy * 32;
    const int tc = threadIdx.x & 31, tr = threadIdx.x >> 5;   // tr in 0..7
#pragma unroll
    for (int i = 0; i < 4; ++i)
        tile[tr + i * 8][tc] = W[(size_t)(r0 + tr + i * 8) * C + c0 + tc];
    __syncthreads();
#pragma unroll
    for (int i = 0; i < 4; ++i)
        Wt[(size_t)(c0 + tr + i * 8) * 768 + r0 + tc] = (__bf16)tile[tc][tr + i * 8];
}

// ---------------- QKV GEMM: 128x128 tile, 3-buffer counted vmcnt (proven best) -----
__global__ __launch_bounds__(256) void gemm_qkv(const __bf16* __restrict__ A,
                                                const __bf16* __restrict__ Bt,
                                                const float* __restrict__ bias,
                                                __bf16* __restrict__ Cout,
                                                int M, int N, int K) {
    __shared__ __align__(16) __bf16 sA[3][128 * 32];
    __shared__ __align__(16) __bf16 sB[3][128 * 32];
    const int t = threadIdx.x, l = t & 63, w = t >> 6;
    const int l31 = l & 31, lh = l >> 5;
    const int wr = w >> 1, wc = w & 1;
    const int xcd = blockIdx.x & 7;
    const int local = blockIdx.x >> 3;
    const int m0 = (xcd * 8 + (local & 7)) * 128;
    const int n0 = (local >> 3) * 128;

    const int r_st = t >> 2;
    const int sw_st = (r_st & 3) ^ ((r_st >> 2) & 3);
    const int g_off = ((t & 3) ^ sw_st) << 3;
    const int sw_rd = (l31 & 3) ^ ((l31 >> 2) & 3);

    f32x16 acc[2][2];
#pragma unroll
    for (int m = 0; m < 2; ++m)
#pragma unroll
        for (int n = 0; n < 2; ++n)
#pragma unroll
            for (int r = 0; r < 16; ++r) acc[m][n][r] = 0.f;

    const int nk = K >> 5;

#pragma unroll
    for (int s = 0; s < 3; ++s) {
        const int k0 = s << 5;
#pragma unroll
        for (int i = 0; i < 2; ++i) {
            int r = i * 64 + r_st;
            gload16(A + (size_t)(m0 + r) * K + k0 + g_off,
                    (char*)&sA[s][0] + (i * 256 + w * 64) * 16);
            gload16(Bt + (size_t)(n0 + r) * K + k0 + g_off,
                    (char*)&sB[s][0] + (i * 256 + w * 64) * 16);
        }
    }

    int cur = 0;
    for (int kt = 0; kt < nk; ++kt) {
        if (kt + 2 < nk)      WAIT_VM(8);
        else if (kt + 1 < nk) WAIT_VM(4);
        else                  WAIT_VM(0);
        __builtin_amdgcn_s_barrier();

        bf16x8 af[2][2], bg[2][2];
#pragma unroll
        for (int m = 0; m < 2; ++m)
#pragma unroll
            for (int ks = 0; ks < 2; ++ks)
                af[m][ks] = *(const bf16x8*)(&sA[cur][(wr * 64 + m * 32 + l31) * 32
                                                      + ((((ks << 1) | lh) ^ sw_rd) << 3)]);
#pragma unroll
        for (int n = 0; n < 2; ++n)
#pragma unroll
            for (int ks = 0; ks < 2; ++ks)
                bg[n][ks] = *(const bf16x8*)(&sB[cur][(wc * 64 + n * 32 + l31) * 32
                                                      + ((((ks << 1) | lh) ^ sw_rd) << 3)]);

#pragma unroll
        for (int ks = 0; ks < 2; ++ks)
#pragma unroll
            for (int m = 0; m < 2; ++m)
#pragma unroll
                for (int n = 0; n < 2; ++n)
                    acc[m][n] = mfma32(af[m][ks], bg[n][ks], acc[m][n]);

        WAIT_LGKM0;
        __builtin_amdgcn_s_barrier();

        if (kt + 3 < nk) {
            const int k0 = (kt + 3) << 5;
#pragma unroll
            for (int i = 0; i < 2; ++i) {
                int r = i * 64 + r_st;
                gload16(A + (size_t)(m0 + r) * K + k0 + g_off,
                        (char*)&sA[cur][0] + (i * 256 + w * 64) * 16);
                gload16(Bt + (size_t)(n0 + r) * K + k0 + g_off,
                        (char*)&sB[cur][0] + (i * 256 + w * 64) * 16);
            }
        }
        cur = (cur == 2) ? 0 : cur + 1;
    }

    // epilogue: 32x32 C layout (m74/m101): col = l31, row = (r&3)+8*(r>>2)+4*lh
#pragma unroll
    for (int n = 0; n < 2; ++n) {
        int col = n0 + wc * 64 + n * 32 + l31;
        float bv = bias[col];
#pragma unroll
        for (int m = 0; m < 2; ++m) {
            int rbase = m0 + wr * 64 + m * 32 + 4 * lh;
#pragma unroll
            for (int r = 0; r < 16; ++r) {
                int row = rbase + (r & 3) + 8 * (r >> 2);
                Cout[(size_t)row * N + col] = (__bf16)(acc[m][n][r] + bv);
            }
        }
    }
}

// ---------------- proj GEMM: 64x128 tile -> 768 blocks = exactly 3/CU (R17) -------
__global__ __launch_bounds__(256) void gemm_proj(const __bf16* __restrict__ A,
                                                 const __bf16* __restrict__ Bt,
                                                 const float* __restrict__ bias,
                                                 float* __restrict__ Cout,
                                                 int M, int N, int K) {
    __shared__ __align__(16) __bf16 sA[3][64 * 32];
    __shared__ __align__(16) __bf16 sB[3][128 * 32];
    const int t = threadIdx.x, l = t & 63, w = t >> 6;
    const int l31 = l & 31, lh = l >> 5;
    const int wr = w >> 1, wc = w & 1;
    const int xcd = blockIdx.x & 7;
    const int local = blockIdx.x >> 3;                 // 0..95
    const int m0 = (xcd * 16 + (local & 15)) * 64;     // 128 m-panels
    const int n0 = (local >> 4) * 128;                 // 6 n-panels

    const int r_st = t >> 2;
    const int sw_st = (r_st & 3) ^ ((r_st >> 2) & 3);
    const int g_off = ((t & 3) ^ sw_st) << 3;
    const int sw_rd = (l31 & 3) ^ ((l31 >> 2) & 3);

    f32x16 acc[2];
#pragma unroll
    for (int n = 0; n < 2; ++n)
#pragma unroll
        for (int r = 0; r < 16; ++r) acc[n][r] = 0.f;

    const int nk = K >> 5;   // 24

#pragma unroll
    for (int s = 0; s < 3; ++s) {
        const int k0 = s << 5;
        gload16(A + (size_t)(m0 + r_st) * K + k0 + g_off,
                (char*)&sA[s][0] + (w * 64) * 16);
#pragma unroll
        for (int i = 0; i < 2; ++i)
            gload16(Bt + (size_t)(n0 + i * 64 + r_st) * K + k0 + g_off,
                    (char*)&sB[s][0] + (i * 256 + w * 64) * 16);
    }

    int cur = 0;
    for (int kt = 0; kt < nk; ++kt) {
        if (kt + 2 < nk)      WAIT_VM(6);
        else if (kt + 1 < nk) WAIT_VM(3);
        else                  WAIT_VM(0);
        __builtin_amdgcn_s_barrier();

        bf16x8 af[2], bg[2][2];
#pragma unroll
        for (int ks = 0; ks < 2; ++ks)
            af[ks] = *(const bf16x8*)(&sA[cur][(wr * 32 + l31) * 32
                                              + ((((ks << 1) | lh) ^ sw_rd) << 3)]);
#pragma unroll
        for (int n = 0; n < 2; ++n)
#pragma unroll
            for (int ks = 0; ks < 2; ++ks)
                bg[n][ks] = *(const bf16x8*)(&sB[cur][(wc * 64 + n * 32 + l31) * 32
                                                      + ((((ks << 1) | lh) ^ sw_rd) << 3)]);

#pragma unroll
        for (int ks = 0; ks < 2; ++ks)
#pragma unroll
            for (int n = 0; n < 2; ++n)
                acc[n] = mfma32(af[ks], bg[n][ks], acc[n]);

        WAIT_LGKM0;
        __builtin_amdgcn_s_barrier();

        if (kt + 3 < nk) {
            const int k0 = (kt + 3) << 5;
            gload16(A + (size_t)(m0 + r_st) * K + k0 + g_off,
                    (char*)&sA[cur][0] + (w * 64) * 16);
#pragma unroll
            for (int i = 0; i < 2; ++i)
                gload16(Bt + (size_t)(n0 + i * 64 + r_st) * K + k0 + g_off,
                        (char*)&sB[cur][0] + (i * 256 + w * 64) * 16);
        }
        cur = (cur == 2) ? 0 : cur + 1;
    }

#pragma unroll
    for (int n = 0; n < 2; ++n) {
        int col = n0 + wc * 64 + n * 32 + l31;
        float bv = bias[col];
        int rbase = m0 + wr * 32 + 4 * lh;
#pragma unroll
        for (int r = 0; r < 16; ++r) {
            int row = rbase + (r & 3) + 8 * (r >> 2);
            Cout[(size_t)row * N + col] = acc[n][r] + bv;
        }
    }
}

// ---------------- causal flash attention — FUSED job pair, single KV sweep ---------
// Block = (pr, h, b), pr in 0..7. Q-tiles A = pr, B = 15-pr. Causality: B's KV range
// (0..15-pr) contains A's (0..pr) -> one sweep t = 0..15-pr; apply tile to A only
// while t <= pr. K/V staged ONCE for the shared prefix: stages/barriers per block
// 17 -> 16-pr (avg 12); shared tiles run 2x compute per barrier.
__global__ __launch_bounds__(256, 2) void attn_fwd(const __bf16* __restrict__ qkv,
                                                   __bf16* __restrict__ y) {
    const int tid = threadIdx.x, l = tid & 63, w = tid >> 6;
    const int lr = l & 15, lk = l >> 4;
    const int r7 = lr & 7;
    const int bid = blockIdx.x;
    const int pr = bid / 96;                 // 0..7
    const int hb = bid % 96;
    const int h = hb % NHEAD;
    const int b = hb / NHEAD;

    __shared__ __align__(16) __bf16 sK[2][64][64];   // chunk-swizzled: phys c = log c ^ (row&7)
    __shared__ __align__(16) __bf16 sV[2][64][64];   // [d][key], XOR-swizzled columns
    __shared__ __align__(16) __bf16 sP[4][16][72];   // per-wave P tile [q][key]

    const size_t baseQ = (size_t)b * T_SEQ * C3 + h * HD;
    const __bf16* Kp = qkv + baseQ + CDIM;
    const __bf16* Vp = qkv + baseQ + 2 * CDIM;

    const int vk0 = tid >> 3;
    const int vc = (tid & 7) << 3;
    const int vg = tid & 7;
    const int krow = tid >> 3;
    const int kchunk = (tid & 7) ^ ((tid >> 3) & 7);

    const int q0A = pr * 64, q0B = (15 - pr) * 64;
    const int ntB = 16 - pr;                 // KV tiles 0..15-pr
    const int qA = q0A + w * 16 + lr;
    const int qB = q0B + w * 16 + lr;

    const size_t rowQA = baseQ + (size_t)(q0A + w * 16 + lr) * C3;
    const size_t rowQB = baseQ + (size_t)(q0B + w * 16 + lr) * C3;
    bf16x8 qaA0 = *(const bf16x8*)(qkv + rowQA + lk * 8);
    bf16x8 qaA1 = *(const bf16x8*)(qkv + rowQA + 32 + lk * 8);
    bf16x8 qaB0 = *(const bf16x8*)(qkv + rowQB + lk * 8);
    bf16x8 qaB1 = *(const bf16x8*)(qkv + rowQB + 32 + lk * 8);
#pragma unroll
    for (int e = 0; e < 8; ++e) {
        qaA0[e] = (__bf16)((float)qaA0[e] * 0.125f);
        qaA1[e] = (__bf16)((float)qaA1[e] * 0.125f);
        qaB0[e] = (__bf16)((float)qaB0[e] * 0.125f);
        qaB1[e] = (__bf16)((float)qaB1[e] * 0.125f);
    }

    f32x4 accA[4], accB[4];
#pragma unroll
    for (int fd = 0; fd < 4; ++fd) {
        accA[fd] = f32x4{0.f, 0.f, 0.f, 0.f};
        accB[fd] = f32x4{0.f, 0.f, 0.f, 0.f};
    }
    float mA = -1e30f, lA = 0.f, mB = -1e30f, lB = 0.f;

    bf16x8 vreg[2];
#pragma unroll
    for (int i = 0; i < 2; ++i)
        vreg[i] = *(const bf16x8*)(Vp + (size_t)(i * 32 + vk0) * C3 + vc);
#pragma unroll
    for (int i = 0; i < 2; ++i)
        gload16(Kp + (size_t)(i * 32 + krow) * C3 + kchunk * 8,
                (char*)&sK[0][0][0] + (i * 256 + w * 64) * 16);
#pragma unroll
    for (int i = 0; i < 2; ++i) {
        int key = i * 32 + vk0;
#pragma unroll
        for (int e = 0; e < 8; ++e)
            sV[0][vc + e][key ^ ((e ^ vg) << 3)] = vreg[i][e];
    }
    __syncthreads();

#pragma unroll 1
    for (int t = 0; t < ntB; ++t) {
        const int kv0 = t * 64;
        const int cur = t & 1, nxt = cur ^ 1;
        const bool pre = (t + 1 < ntB);
        if (pre) {
            const int kvp = kv0 + 64;
#pragma unroll
            for (int i = 0; i < 2; ++i)
                vreg[i] = *(const bf16x8*)(Vp + (size_t)(kvp + i * 32 + vk0) * C3 + vc);
#pragma unroll
            for (int i = 0; i < 2; ++i)
                gload16(Kp + (size_t)(kvp + i * 32 + krow) * C3 + kchunk * 8,
                        (char*)&sK[nxt][0][0] + (i * 256 + w * 64) * 16);
        }

        // ================= Q-tile B (always active) =================
        {
            f32x4 s[4];
            __builtin_amdgcn_s_setprio(1);
#pragma unroll
            for (int fc = 0; fc < 4; ++fc) {
                const __bf16* kr = &sK[cur][fc * 16 + lr][0];
                bf16x8 k0 = *(const bf16x8*)(kr + ((lk ^ r7) << 3));
                bf16x8 k1 = *(const bf16x8*)(kr + (((4 + lk) ^ r7) << 3));
                f32x4 z = f32x4{0.f, 0.f, 0.f, 0.f};
                z = mfma_bf16(k0, qaB0, z);
                z = mfma_bf16(k1, qaB1, z);
                s[fc] = z;
            }
            __builtin_amdgcn_s_setprio(0);
            float ps[4][4];
#pragma unroll
            for (int fc = 0; fc < 4; ++fc)
#pragma unroll
                for (int j = 0; j < 4; ++j) ps[fc][j] = s[fc][j];
            if (t == ntB - 1) {
#pragma unroll
                for (int fc = 0; fc < 4; ++fc)
#pragma unroll
                    for (int j = 0; j < 4; ++j) {
                        int key = kv0 + fc * 16 + lk * 4 + j;
                        if (key > qB) ps[fc][j] = -1e30f;
                    }
            }
            float mfc[4];
#pragma unroll
            for (int fc = 0; fc < 4; ++fc)
                mfc[fc] = fmaxf(fmaxf(ps[fc][0], ps[fc][1]), fmaxf(ps[fc][2], ps[fc][3]));
            float mt = fmaxf(fmaxf(mfc[0], mfc[1]), fmaxf(mfc[2], mfc[3]));
            mt = fmaxf(mt, __shfl_xor(mt, 16, 64));
            mt = fmaxf(mt, __shfl_xor(mt, 32, 64));
            if (!__all(mt - mB <= 8.f)) {
                const float mn = fmaxf(mB, mt);
                const float corr = __expf(mB - mn);
                mB = mn;
                lB *= corr;
                float cj[4];
#pragma unroll
                for (int j = 0; j < 4; ++j) cj[j] = __shfl(corr, lk * 4 + j, 64);
#pragma unroll
                for (int fd = 0; fd < 4; ++fd)
#pragma unroll
                    for (int j = 0; j < 4; ++j) accB[fd][j] *= cj[j];
            }
            float rs = 0.f;
#pragma unroll
            for (int fc = 0; fc < 4; ++fc)
#pragma unroll
                for (int j = 0; j < 4; ++j) {
                    float p = __expf(ps[fc][j] - mB);
                    ps[fc][j] = p;
                    rs += p;
                }
            rs += __shfl_xor(rs, 16, 64);
            rs += __shfl_xor(rs, 32, 64);
            lB += rs;
#pragma unroll
            for (int fc = 0; fc < 4; ++fc)
#pragma unroll
                for (int jp = 0; jp < 2; ++jp) {
                    bf16x2 pk = { (__bf16)ps[fc][jp * 2], (__bf16)ps[fc][jp * 2 + 1] };
                    *(bf16x2*)&sP[w][lr][fc * 16 + lk * 4 + jp * 2] = pk;
                }
            __builtin_amdgcn_s_setprio(1);
#pragma unroll
            for (int ks = 0; ks < 2; ++ks) {
                bf16x8 pa = *(const bf16x8*)&sP[w][lr][ks * 32 + lk * 8];
#pragma unroll
                for (int fd = 0; fd < 4; ++fd) {
                    int d = fd * 16 + lr;
                    int sw = ((d & 7) ^ ((d >> 3) & 7)) << 3;
                    bf16x8 vb = *(const bf16x8*)&sV[cur][d][(ks * 32 + lk * 8) ^ sw];
                    accB[fd] = mfma_bf16(pa, vb, accB[fd]);
                }
            }
            __builtin_amdgcn_s_setprio(0);
        }

        // ================= Q-tile A (shared prefix t <= pr) =================
        if (t <= pr) {
            f32x4 s[4];
            __builtin_amdgcn_s_setprio(1);
#pragma unroll
            for (int fc = 0; fc < 4; ++fc) {
                const __bf16* kr = &sK[cur][fc * 16 + lr][0];
                bf16x8 k0 = *(const bf16x8*)(kr + ((lk ^ r7) << 3));
                bf16x8 k1 = *(const bf16x8*)(kr + (((4 + lk) ^ r7) << 3));
                f32x4 z = f32x4{0.f, 0.f, 0.f, 0.f};
                z = mfma_bf16(k0, qaA0, z);
                z = mfma_bf16(k1, qaA1, z);
                s[fc] = z;
            }
            __builtin_amdgcn_s_setprio(0);
            float ps[4][4];
#pragma unroll
            for (int fc = 0; fc < 4; ++fc)
#pragma unroll
                for (int j = 0; j < 4; ++j) ps[fc][j] = s[fc][j];
            if (t == pr) {
#pragma unroll
                for (int fc = 0; fc < 4; ++fc)
#pragma unroll
                    for (int j = 0; j < 4; ++j) {
                        int key = kv0 + fc * 16 + lk * 4 + j;
                        if (key > qA) ps[fc][j] = -1e30f;
                    }
            }
            float mfc[4];
#pragma unroll
            for (int fc = 0; fc < 4; ++fc)
                mfc[fc] = fmaxf(fmaxf(ps[fc][0], ps[fc][1]), fmaxf(ps[fc][2], ps[fc][3]));
            float mt = fmaxf(fmaxf(mfc[0], mfc[1]), fmaxf(mfc[2], mfc[3]));
            mt = fmaxf(mt, __shfl_xor(mt, 16, 64));
            mt = fmaxf(mt, __shfl_xor(mt, 32, 64));
            if (!__all(mt - mA <= 8.f)) {
                const float mn = fmaxf(mA, mt);
                const float corr = __expf(mA - mn);
                mA = mn;
                lA *= corr;
                float cj[4];
#pragma unroll
                for (int j = 0; j < 4; ++j) cj[j] = __shfl(corr, lk * 4 + j, 64);
#pragma unroll
                for (int fd = 0; fd < 4; ++fd)
#pragma unroll
                    for (int j = 0; j < 4; ++j) accA[fd][j] *= cj[j];
            }
            float rs = 0.f;
#pragma unroll
            for (int fc = 0; fc < 4; ++fc)
#pragma unroll
                for (int j = 0; j < 4; ++j) {
                    float p = __expf(ps[fc][j] - mA);
                    ps[fc][j] = p;
                    rs += p;
                }
            rs += __shfl_xor(rs, 16, 64);
            rs += __shfl_xor(rs, 32, 64);
            lA += rs;
#pragma unroll
            for (int fc = 0; fc < 4; ++fc)
#pragma unroll
                for (int jp = 0; jp < 2; ++jp) {
                    bf16x2 pk = { (__bf16)ps[fc][jp * 2], (__bf16)ps[fc][jp * 2 + 1] };
                    *(bf16x2*)&sP[w][lr][fc * 16 + lk * 4 + jp * 2] = pk;
                }
            __builtin_amdgcn_s_setprio(1);
#pragma unroll
            for (int ks = 0; ks < 2; ++ks) {
                bf16x8 pa = *(const bf16x8*)&sP[w][lr][ks * 32 + lk * 8];
#pragma unroll
                for (int fd = 0; fd < 4; ++fd) {
                    int d = fd * 16 + lr;
                    int sw = ((d & 7) ^ ((d >> 3) & 7)) << 3;
                    bf16x8 vb = *(const bf16x8*)&sV[cur][d][(ks * 32 + lk * 8) ^ sw];
                    accA[fd] = mfma_bf16(pa, vb, accA[fd]);
                }
            }
            __builtin_amdgcn_s_setprio(0);
        }

        if (pre) {
#pragma unroll
            for (int i = 0; i < 2; ++i) {
                int key = i * 32 + vk0;
#pragma unroll
                for (int e = 0; e < 8; ++e)
                    sV[nxt][vc + e][key ^ ((e ^ vg) << 3)] = vreg[i][e];
            }
        }
        __syncthreads();
    }

    {
        float linv[4];
#pragma unroll
        for (int j = 0; j < 4; ++j) linv[j] = 1.f / __shfl(lA, lk * 4 + j, 64);
        const size_t yrow0 = (size_t)(b * T_SEQ + q0A + w * 16 + lk * 4);
#pragma unroll
        for (int fd = 0; fd < 4; ++fd) {
            int col = h * HD + fd * 16 + lr;
#pragma unroll
            for (int j = 0; j < 4; ++j)
                y[(yrow0 + j) * CDIM + col] = (__bf16)(accA[fd][j] * linv[j]);
        }
    }
    {
        float linv[4];
#pragma unroll
        for (int j = 0; j < 4; ++j) linv[j] = 1.f / __shfl(lB, lk * 4 + j, 64);
        const size_t yrow0 = (size_t)(b * T_SEQ + q0B + w * 16 + lk * 4);
#pragma unroll
        for (int fd = 0; fd < 4; ++fd) {
            int col = h * HD + fd * 16 + lr;
#pragma unroll
            for (int j = 0; j < 4; ++j)
                y[(yrow0 + j) * CDIM + col] = (__bf16)(accB[fd][j] * linv[j]);
        }
    }
}

// ---------------- launch ----------------
extern "C" void kernel_launch(void* const* d_in, const int* in_sizes, int n_in,
                              void* d_out, int out_size, void* d_ws, size_t ws_size,
                              hipStream_t stream) {
    const float* x      = (const float*)d_in[0];
    const float* W_attn = (const float*)d_in[1];
    const float* b_attn = (const float*)d_in[2];
    const float* W_proj = (const float*)d_in[3];
    const float* b_proj = (const float*)d_in[4];

    __bf16* xb  = (__bf16*)d_ws;                       // [8192][768]
    __bf16* Wat = xb  + (size_t)8192 * 768;            // [2304][768]  (W_attn^T)
    __bf16* Wpt = Wat + (size_t)2304 * 768;            // [768][768]   (W_proj^T)
    __bf16* qkv = Wpt + (size_t)768 * 768;             // [8192][2304]
    __bf16* yb  = qkv + (size_t)8192 * 2304;           // [8192][768]

    prep<<<6144 + 2304, 256, 0, stream>>>(x, xb, W_attn, Wat, W_proj, Wpt);
    gemm_qkv<<<18 * 64, 256, 0, stream>>>(xb, Wat, b_attn, qkv, 8192, 2304, 768);
    attn_fwd<<<NBATCH * NHEAD * 8, 256, 0, stream>>>(qkv, yb);
    gemm_proj<<<768, 256, 0, stream>>>(yb, Wpt, b_proj, (float*)d_out, 8192, 768, 768);
}